// Round 6
// baseline (271.246 us; speedup 1.0000x reference)
//
#include <hip/hip_runtime.h>

#ifndef __has_builtin
#define __has_builtin(x) 0
#endif

__device__ __forceinline__ float fast_exp2(float x) {
#if __has_builtin(__builtin_amdgcn_exp2f)
    return __builtin_amdgcn_exp2f(x);
#else
    return exp2f(x);
#endif
}

constexpr int   kB      = 256;
constexpr int   kC      = 1024;
constexpr int   kG      = 13;
constexpr int   kP      = kG * kG;                // 169
constexpr int   kRows   = kB * kP;                // 43264
constexpr float kEps    = 1e-6f;
constexpr float kZ      = 17.079468445347132f;    // 2*pi*e
constexpr float kLog2e  = 1.4426950408889634f;
constexpr float kInv169 = 1.0f / 169.0f;
constexpr float kScale  = 1.0f / (256.0f * 1024.0f);

// ---------------------------------------------------------------------------
// Pass 1: invD(b,p) = 1 / sum_c exp(x). Wave per row, 4 rows per 256-thread
// block, grid 10816 -> massive TLP (32 waves/CU at (256,8)), 4 KB in flight
// per wave. This shape has consistently run at streaming rate.
// ---------------------------------------------------------------------------
__global__ __launch_bounds__(256, 8)
void rowsum_kernel(const float* __restrict__ x, float* __restrict__ invD)
{
    const int tid  = threadIdx.x;
    const int lane = tid & 63;
    const int wid  = tid >> 6;
    const int row  = blockIdx.x * 4 + wid;          // row = b*169 + p

    const float4* __restrict__ src = (const float4*)(x + (size_t)row * kC);
    float4 v0 = src[lane];
    float4 v1 = src[lane + 64];
    float4 v2 = src[lane + 128];
    float4 v3 = src[lane + 192];

    float s =
        (fast_exp2(v0.x * kLog2e) + fast_exp2(v0.y * kLog2e)) +
        (fast_exp2(v0.z * kLog2e) + fast_exp2(v0.w * kLog2e)) +
        (fast_exp2(v1.x * kLog2e) + fast_exp2(v1.y * kLog2e)) +
        (fast_exp2(v1.z * kLog2e) + fast_exp2(v1.w * kLog2e)) +
        (fast_exp2(v2.x * kLog2e) + fast_exp2(v2.y * kLog2e)) +
        (fast_exp2(v2.z * kLog2e) + fast_exp2(v2.w * kLog2e)) +
        (fast_exp2(v3.x * kLog2e) + fast_exp2(v3.y * kLog2e)) +
        (fast_exp2(v3.z * kLog2e) + fast_exp2(v3.w * kLog2e));

    #pragma unroll
    for (int m = 1; m < 64; m <<= 1)
        s += __shfl_xor(s, m);

    if (lane == 0) invD[row] = 1.0f / s;
}

// ---------------------------------------------------------------------------
// Pass 2: per-(b,c) moments. Block = (batch b, chunk of 256 channels);
// grid 1024 (4 blocks/CU), 256 threads, __launch_bounds__(256,8) -> up to
// 32 waves/CU. Thread owns one channel; h-loop '#pragma unroll 1' with
// 13-deep prefetch of the next h-row (13 x 256B wave-loads in flight).
// Input re-read comes mostly from L3 (177 MB < 256 MB, just streamed by
// pass 1). invD broadcast from LDS; weights are compile-time constants in
// the unrolled inner loop. Zero cross-lane ops until the tiny epilogue.
// ---------------------------------------------------------------------------
__global__ __launch_bounds__(256, 8)
void moments_kernel(const float* __restrict__ x, const float* __restrict__ invD,
                    float* __restrict__ out)
{
    __shared__ float sInv[kP];
    __shared__ float sred[4];

    const int tid   = threadIdx.x;
    const int lane  = tid & 63;
    const int wid   = tid >> 6;
    const int b     = blockIdx.x >> 2;
    const int chunk = blockIdx.x & 3;

    if (tid < kP) sInv[tid] = invD[b * kP + tid];
    __syncthreads();

    const float* __restrict__ xc = x + (size_t)b * kP * kC + chunk * 256 + tid;

    float S0 = 0.f, S1x = 0.f, S2x = 0.f, S1y = 0.f, S2y = 0.f;

    float v[kG], vn[kG];
    #pragma unroll
    for (int w = 0; w < kG; ++w)
        v[w] = xc[(size_t)w * kC];

    #pragma unroll 1
    for (int h = 0; h < kG; ++h) {
        if (h + 1 < kG) {
            const float* __restrict__ rn = xc + (size_t)(h + 1) * kG * kC;
            #pragma unroll
            for (int w = 0; w < kG; ++w)
                vn[w] = rn[(size_t)w * kC];
        }

        float t0 = 0.f, t1 = 0.f, t2 = 0.f;
        #pragma unroll
        for (int w = 0; w < kG; ++w) {
            const float e = fast_exp2(v[w] * kLog2e) * sInv[h * kG + w];
            t0 += e;
            t1 = fmaf((float)(w + 1), e, t1);
            t2 = fmaf((float)((w + 1) * (w + 1)), e, t2);
        }
        const float fx = (float)(h + 1);
        S0  += t0;
        S1x  = fmaf(fx,      t0, S1x);
        S2x  = fmaf(fx * fx, t0, S2x);
        S1y += t1;
        S2y += t2;

        #pragma unroll
        for (int w = 0; w < kG; ++w)
            v[w] = vn[w];
    }

    // per-channel det, then 4-wave block reduce
    const float s   = S0 + kEps;
    const float is  = 1.0f / s;
    const float mx  = S1x * is;
    const float my  = S1y * is;
    const float nx  = S2x - mx * (2.0f * S1x - mx * S0);
    const float ny  = S2y - my * (2.0f * S1y - my * S0);
    const float t   = (nx + ny) * is * kInv169;   // x_var + y_var
    float det = t * t * kZ;

    #pragma unroll
    for (int m = 1; m < 64; m <<= 1)
        det += __shfl_xor(det, m);

    if (lane == 0) sred[wid] = det;
    __syncthreads();
    if (tid == 0)
        atomicAdd(out, (sred[0] + sred[1] + sred[2] + sred[3]) * kScale);
}

extern "C" void kernel_launch(void* const* d_in, const int* in_sizes, int n_in,
                              void* d_out, int out_size, void* d_ws, size_t ws_size,
                              hipStream_t stream)
{
    const float* x    = (const float*)d_in[0];
    float*       out  = (float*)d_out;
    float*       invD = (float*)d_ws;   // kRows floats = 173 KB scratch

    hipMemsetAsync(out, 0, sizeof(float) * (size_t)out_size, stream);
    rowsum_kernel <<<dim3(kRows / 4), dim3(256), 0, stream>>>(x, invD);
    moments_kernel<<<dim3(kB * 4),    dim3(256), 0, stream>>>(x, invD, out);
}

// Round 7
// 261.679 us; speedup vs baseline: 1.0366x; 1.0366x over previous
//
#include <hip/hip_runtime.h>

#ifndef __has_builtin
#define __has_builtin(x) 0
#endif

__device__ __forceinline__ float fast_exp2(float x) {
#if __has_builtin(__builtin_amdgcn_exp2f)
    return __builtin_amdgcn_exp2f(x);
#else
    return exp2f(x);
#endif
}

// Canonical CDNA wave64 sum via DPP (VALU pipe, not DS):
// row_shr 1/2/4/8 (bound_ctrl: invalid->0), then row_bcast15 (rows 1,3),
// row_bcast31 (rows 2,3). Lane 63 ends with the full 64-lane sum.
__device__ __forceinline__ float wave_sum_dpp(float x) {
    int v;
    v = __builtin_amdgcn_update_dpp(0, __float_as_int(x), 0x111, 0xf, 0xf, true);
    x += __int_as_float(v);
    v = __builtin_amdgcn_update_dpp(0, __float_as_int(x), 0x112, 0xf, 0xf, true);
    x += __int_as_float(v);
    v = __builtin_amdgcn_update_dpp(0, __float_as_int(x), 0x114, 0xf, 0xf, true);
    x += __int_as_float(v);
    v = __builtin_amdgcn_update_dpp(0, __float_as_int(x), 0x118, 0xf, 0xf, true);
    x += __int_as_float(v);
    v = __builtin_amdgcn_update_dpp(0, __float_as_int(x), 0x142, 0xa, 0xf, false);
    x += __int_as_float(v);
    v = __builtin_amdgcn_update_dpp(0, __float_as_int(x), 0x143, 0xc, 0xf, false);
    x += __int_as_float(v);
    return x;
}

constexpr int   kB      = 256;
constexpr int   kC      = 1024;
constexpr int   kG      = 13;
constexpr int   kP      = kG * kG;                // 169
constexpr int   kParts  = 4;
constexpr int   kMaxPP  = 43;                     // parts cover 42,42,42,43
constexpr float kEps    = 1e-6f;
constexpr float kZ      = 17.079468445347132f;    // 2*pi*e
constexpr float kLog2e  = 1.4426950408889634f;
constexpr float kInv169 = 1.0f / 169.0f;
constexpr float kScale  = 1.0f / (256.0f * 1024.0f);

// ---------------------------------------------------------------------------
// Kernel 1: single-HBM-read partial stats (R4 structure, DS-storm removed).
// Block = (b, part), 1024 threads, thread owns channel c = tid.
// e[43] held in VGPRs; per-position 1024-channel denominator =
// DPP wave-reduce (6 VALU adds) -> lane-63 LDS write (1 DS op) -> 16-way
// tree by 43 threads -> invD LDS broadcast. Input bytes touched exactly once.
// ---------------------------------------------------------------------------
__global__ __launch_bounds__(1024, 4)
void part_stats_kernel(const float* __restrict__ x, float* __restrict__ ws)
{
    __shared__ float sP[kMaxPP * 16];     // per-(position, wave) partial sums
    __shared__ float sInvD[kMaxPP];

    const int tid   = threadIdx.x;
    const int lane  = tid & 63;
    const int wid   = tid >> 6;
    const int b     = blockIdx.x >> 2;
    const int part  = blockIdx.x & 3;
    const int start = part * 42;
    const bool full = (part == 3);        // part 3 owns 43 positions

    const float* __restrict__ xc = x + (size_t)b * kP * kC + (size_t)start * kC + tid;

    float e[kMaxPP];
    #pragma unroll
    for (int i = 0; i < kMaxPP; ++i)
        e[i] = xc[(size_t)i * kC];        // p = start+i <= 168 always in-bounds

    #pragma unroll
    for (int i = 0; i < kMaxPP; ++i)
        e[i] = fast_exp2(e[i] * kLog2e);

    if (!full) e[42] = 0.0f;              // mask the duplicated position

    // per-position wave partial sums on the VALU pipe
    #pragma unroll
    for (int i = 0; i < kMaxPP; ++i) {
        const float s = wave_sum_dpp(e[i]);
        if (lane == 63) sP[i * 16 + wid] = s;
    }
    __syncthreads();

    if (tid < kMaxPP) {
        float d = 0.f;
        #pragma unroll
        for (int w = 0; w < 16; ++w)
            d += sP[tid * 16 + w];
        sInvD[tid] = 1.0f / (d + 1e-30f); // masked position: 0 * huge = 0
    }
    __syncthreads();

    float S0 = 0.f, S1x = 0.f, S1y = 0.f, S2x = 0.f, S2y = 0.f;
    #pragma unroll
    for (int i = 0; i < kMaxPP; ++i) {
        const float f  = e[i] * sInvD[i];
        const int   p  = start + i;       // compile-time-ish; /13 -> magic mul
        const int   h  = p / kG;
        const int   w  = p - h * kG;
        const float fx = (float)(h + 1);
        const float fy = (float)(w + 1);
        S0  += f;
        S1x  = fmaf(fx,      f, S1x);
        S1y  = fmaf(fy,      f, S1y);
        S2x  = fmaf(fx * fx, f, S2x);
        S2y  = fmaf(fy * fy, f, S2y);
    }

    // partial stats: ws[part][b][stat][c]
    float* __restrict__ o = ws + (((size_t)part * kB + b) * 5) * kC + tid;
    o[0 * kC] = S0;
    o[1 * kC] = S1x;
    o[2 * kC] = S1y;
    o[3 * kC] = S2x;
    o[4 * kC] = S2y;
}

// ---------------------------------------------------------------------------
// Kernel 2: combine 4 parts per (b,c), det epilogue, global mean.
// ---------------------------------------------------------------------------
__global__ __launch_bounds__(1024, 4)
void combine_kernel(const float* __restrict__ ws, float* __restrict__ out)
{
    __shared__ float sred[16];

    const int tid  = threadIdx.x;
    const int lane = tid & 63;
    const int wid  = tid >> 6;
    const int b    = blockIdx.x;

    float S0 = 0.f, S1x = 0.f, S1y = 0.f, S2x = 0.f, S2y = 0.f;
    #pragma unroll
    for (int part = 0; part < kParts; ++part) {
        const float* __restrict__ o = ws + (((size_t)part * kB + b) * 5) * kC + tid;
        S0  += o[0 * kC];
        S1x += o[1 * kC];
        S1y += o[2 * kC];
        S2x += o[3 * kC];
        S2y += o[4 * kC];
    }

    const float s   = S0 + kEps;
    const float is  = 1.0f / s;
    const float mx  = S1x * is;
    const float my  = S1y * is;
    const float nx  = S2x - mx * (2.0f * S1x - mx * S0);
    const float ny  = S2y - my * (2.0f * S1y - my * S0);
    const float t   = (nx + ny) * is * kInv169;
    float det = t * t * kZ;

    #pragma unroll
    for (int m = 1; m < 64; m <<= 1)
        det += __shfl_xor(det, m);

    if (lane == 0) sred[wid] = det;
    __syncthreads();
    if (wid == 0) {
        float v = (lane < 16) ? sred[lane] : 0.0f;
        #pragma unroll
        for (int m = 1; m < 16; m <<= 1)
            v += __shfl_xor(v, m);
        if (lane == 0) atomicAdd(out, v * kScale);
    }
}

extern "C" void kernel_launch(void* const* d_in, const int* in_sizes, int n_in,
                              void* d_out, int out_size, void* d_ws, size_t ws_size,
                              hipStream_t stream)
{
    const float* x   = (const float*)d_in[0];
    float*       out = (float*)d_out;
    float*       ws  = (float*)d_ws;   // 4*256*5*1024 floats = 20 MB

    hipMemsetAsync(out, 0, sizeof(float) * (size_t)out_size, stream);
    part_stats_kernel<<<dim3(kB * kParts), dim3(1024), 0, stream>>>(x, ws);
    combine_kernel  <<<dim3(kB),           dim3(1024), 0, stream>>>(ws, out);
}